// Round 7
// baseline (171.670 us; speedup 1.0000x reference)
//
#include <hip/hip_runtime.h>

// GMELoss3D: fused 3D Sobel edge-magnitude MSE on [2,2,128,128,128] fp32 volumes.
// R7: float2-per-lane full-row waves. One wave covers a whole 128-wide x-row
// (lane owns cols 2i,2i+1), marching ZC=8 z-planes. vs R6: VMEM instrs halved
// (dwordx2), shuffles halved (neighbor cols mostly in-lane), x-junction halo
// path deleted (no segment seam). Barrier-free z-loop, distance-2 prefetch,
// mod-3 combo rotation, fully unrolled 10-step loop.
//
// Separable decomposition (s=[1,2,1], d=[-1,0,1], e=[1,1,1]); per column:
// ys,yd,ye from 3 rows -> x-combines (shfl at lane seams) -> z-combines.
// Verified exact (absmax 0.0) in R5/R6.

namespace {

constexpr int YX = 128 * 128;
constexpr ptrdiff_t CS = (ptrdiff_t)128 * YX;    // channel stride
constexpr int ZC = 8;                            // z-planes per wave
constexpr float INV_N = 1.0f / 4194304.0f;

struct V2 { float x, y; };
__device__ __forceinline__ V2 v2(float a, float b) { V2 r; r.x = a; r.y = b; return r; }
__device__ __forceinline__ V2 operator+(V2 a, V2 b) { return v2(a.x + b.x, a.y + b.y); }
__device__ __forceinline__ V2 operator-(V2 a, V2 b) { return v2(a.x - b.x, a.y - b.y); }
__device__ __forceinline__ V2 operator*(float a, V2 b) { return v2(a * b.x, a * b.y); }
__device__ __forceinline__ V2 fma2(float a, V2 b, V2 c) {
  return v2(__builtin_fmaf(a, b.x, c.x), __builtin_fmaf(a, b.y, c.y));
}
__device__ __forceinline__ V2 fma2v(V2 a, V2 b, V2 c) {
  return v2(__builtin_fmaf(a.x, b.x, c.x), __builtin_fmaf(a.y, b.y, c.y));
}

// half edge magnitude (mag / C, C=2) from 3 planes' combos (a=z-1, b=z, c=z+1)
__device__ __forceinline__ V2 edge_mag_half(const V2* __restrict__ Ca,
                                            const V2* __restrict__ Cb,
                                            const V2* __restrict__ Cc) {
  const V2 g1  = fma2(2.0f, Cb[0], Ca[0] + Cc[0]);   // Sx
  const V2 g2  = fma2(2.0f, Cb[1], Ca[1] + Cc[1]);   // Sy
  const V2 g3  = Cc[2] - Ca[2];                      // Sz
  const V2 Azx = fma2(2.0f, Cb[3], Ca[3] + Cc[3]);   // s_z e_y d_x
  const V2 Azy = fma2(2.0f, Cb[4], Ca[4] + Cc[4]);   // s_z d_y e_x
  const V2 Axz = Cc[5] - Ca[5];                      // d_z e_y s_x
  const V2 Axy = g2 - Cb[1];                         // e_z d_y s_x
  const V2 Ayx = g1 - Cb[0];                         // e_z s_y d_x
  const V2 Ayz = Cc[6] - Ca[6];                      // d_z s_y e_x
  const V2 g4 = Azx - Azy, g5 = Azx + Azy;           // Sd11, Sd12
  const V2 g6 = Axz - Axy, g7 = Axz + Axy;           // Sd21, Sd22
  const V2 g8 = Ayx - Ayz, g9 = Ayx + Ayz;           // Sd31, Sd32
  V2 s = fma2v(g1, g1, v2(1e-12f, 1e-12f));
  s = fma2v(g2, g2, s); s = fma2v(g3, g3, s);
  s = fma2v(g4, g4, s); s = fma2v(g5, g5, s);
  s = fma2v(g6, g6, s); s = fma2v(g7, g7, s);
  s = fma2v(g8, g8, s); s = fma2v(g9, g9, s);
  return v2(0.5f * sqrtf(s.x), 0.5f * sqrtf(s.y));
}

// 7 plane-combos for this lane's 2 columns from channel-summed rows s0,s1,s2
__device__ __forceinline__ void combos7(V2 s0, V2 s1, V2 s2,
                                        bool l0, bool l63,
                                        V2* __restrict__ C) {
  const V2 t  = s0 + s2;
  const V2 ys = fma2(2.0f, s1, t);
  const V2 ye = t + s1;
  const V2 yd = s2 - s0;
  // neighbor columns: left of col0 = prev lane's col1; right of col1 = next's col0
  float ysLx = __shfl_up(ys.y, 1),  ydLx = __shfl_up(yd.y, 1),  yeLx = __shfl_up(ye.y, 1);
  float ysRy = __shfl_down(ys.x, 1), ydRy = __shfl_down(yd.x, 1), yeRy = __shfl_down(ye.x, 1);
  if (l0)  { ysLx = 0.0f; ydLx = 0.0f; yeLx = 0.0f; }   // x=0 boundary
  if (l63) { ysRy = 0.0f; ydRy = 0.0f; yeRy = 0.0f; }   // x=127 boundary
  const V2 ysL = v2(ysLx, ys.x), ysR = v2(ys.y, ysRy);
  const V2 ydL = v2(ydLx, yd.x), ydR = v2(yd.y, ydRy);
  const V2 yeL = v2(yeLx, ye.x), yeR = v2(ye.y, yeRy);
  C[0] = ysR - ysL;                 // s_y d_x
  const V2 tds = ydL + ydR;
  C[1] = fma2(2.0f, yd, tds);       // d_y s_x
  C[4] = tds + yd;                  // d_y e_x
  const V2 tss = ysL + ysR;
  C[2] = fma2(2.0f, ys, tss);       // s_y s_x
  C[6] = tss + ys;                  // s_y e_x
  C[3] = yeR - yeL;                 // e_y d_x
  const V2 tes = yeL + yeR;
  C[5] = fma2(2.0f, ye, tes);       // e_y s_x
}

__global__ __launch_bounds__(256, 3)
void gme_loss_kernel(const float* __restrict__ y,
                     const float* __restrict__ yp,
                     float* __restrict__ out) {
  const int tid  = threadIdx.x;
  const int lane = tid & 63;
  const int wv   = tid >> 6;                    // 0..3, wave id in block
  const int yy   = blockIdx.x * 4 + wv;         // this wave's row (W axis)
  const int z0   = blockIdx.y * ZC;             // z-chunk base
  const int b    = blockIdx.z;                  // batch
  const int px   = 2 * lane;                    // first of this lane's 2 columns
  const bool l0 = (lane == 0), l63 = (lane == 63);
  const float w0 = (yy > 0)   ? 1.0f : 0.0f;    // y boundary masks
  const float w2 = (yy < 127) ? 1.0f : 0.0f;
  const int r0 = (yy > 0) ? yy - 1 : 0;
  const int r2 = (yy < 127) ? yy + 1 : 127;

  const float* Yb = y  + (ptrdiff_t)b * 2 * CS;
  const float* Pb = yp + (ptrdiff_t)b * 2 * CS;
  const int o0 = r0 * 128 + px;
  const int o1 = yy * 128 + px;
  const int o2 = r2 * 128 + px;

  V2 arA[12], arB[12];
#pragma unroll
  for (int j = 0; j < 12; ++j) { arA[j] = v2(0.f, 0.f); arB[j] = v2(0.f, 0.f); }

  auto issue = [&](int zl, V2* __restrict__ a) {
    if ((unsigned)zl < 128u) {
      const float* Yz = Yb + (ptrdiff_t)zl * YX;
      const float* Pz = Pb + (ptrdiff_t)zl * YX;
      a[0]  = *(const V2*)(Yz + o0); a[1]  = *(const V2*)(Yz + o0 + CS);
      a[2]  = *(const V2*)(Yz + o1); a[3]  = *(const V2*)(Yz + o1 + CS);
      a[4]  = *(const V2*)(Yz + o2); a[5]  = *(const V2*)(Yz + o2 + CS);
      a[6]  = *(const V2*)(Pz + o0); a[7]  = *(const V2*)(Pz + o0 + CS);
      a[8]  = *(const V2*)(Pz + o1); a[9]  = *(const V2*)(Pz + o1 + CS);
      a[10] = *(const V2*)(Pz + o2); a[11] = *(const V2*)(Pz + o2 + CS);
    } else {
#pragma unroll
      for (int j = 0; j < 12; ++j) a[j] = v2(0.f, 0.f);
    }
  };

  V2 KY[3][7], KP[3][7];
  float acc = 0.0f;

  // prologue: distance-2 pipeline
  issue(z0 - 1, arA);             // consumed i=0
  issue(z0,     arB);             // consumed i=1

#pragma unroll
  for (int i = 0; i < ZC + 2; ++i) {            // 10 steps, plane zc = z0-1+i
    const int zc = z0 - 1 + i;
    V2* a = (i & 1) ? arB : arA;
    // consume plane zc: channel sums + y-boundary masks
    const V2 sY0 = w0 * (a[0] + a[1]);
    const V2 sY1 = a[2] + a[3];
    const V2 sY2 = w2 * (a[4] + a[5]);
    const V2 sP0 = w0 * (a[6] + a[7]);
    const V2 sP1 = a[8] + a[9];
    const V2 sP2 = w2 * (a[10] + a[11]);
    // refill this buffer for plane zc+2 (in flight across next step)
    issue((i <= ZC - 1) ? (zc + 2) : 128, a);
    combos7(sY0, sY1, sY2, l0, l63, KY[i % 3]);
    combos7(sP0, sP1, sP2, l0, l63, KP[i % 3]);
    if (i >= 2) {                                // emit output plane zc-1
      const V2 my = edge_mag_half(KY[(i + 1) % 3], KY[(i + 2) % 3], KY[i % 3]);
      const V2 mp = edge_mag_half(KP[(i + 1) % 3], KP[(i + 2) % 3], KP[i % 3]);
      const V2 d = my - mp;
      acc = __builtin_fmaf(d.x, d.x, acc);
      acc = __builtin_fmaf(d.y, d.y, acc);
    }
  }

  // ---- per-wave reduce, then one atomic per block ----
#pragma unroll
  for (int off = 32; off > 0; off >>= 1) acc += __shfl_down(acc, off);
  __shared__ float red[4];
  if (lane == 0) red[wv] = acc;
  __syncthreads();
  if (tid == 0) atomicAdd(out, (red[0] + red[1] + red[2] + red[3]) * INV_N);
}

}  // namespace

extern "C" void kernel_launch(void* const* d_in, const int* in_sizes, int n_in,
                              void* d_out, int out_size, void* d_ws, size_t ws_size,
                              hipStream_t stream) {
  const float* y  = (const float*)d_in[0];
  const float* yp = (const float*)d_in[1];
  float* out = (float*)d_out;

  // d_out is poisoned before every launch: zero via memset node (graph-capturable)
  hipMemsetAsync(out, 0, sizeof(float), stream);

  dim3 block(256, 1, 1);                        // 4 waves, each owns one full row
  dim3 grid(32,                                 // 128 rows / 4 per block
            16,                                 // 16 z-chunks (ZC=8)
            2);                                 // batch
  gme_loss_kernel<<<grid, block, 0, stream>>>(y, yp, out);
}